// Round 1
// baseline (278.811 us; speedup 1.0000x reference)
//
#include <hip/hip_runtime.h>

// SeesawLoss on MI355X.
// Inputs: d_in[0] = cls_score fp32 (8,16,512,512), d_in[1] = labels i32 (8,512,512),
//         d_in[2] = cum_samples fp32 (16). Output: d_out[0] = scalar loss fp32.
// ws layout (uint32 words): [0..15] class histogram, [16] sum_nll (f32), [17] sum_mask (f32)

constexpr int   kC      = 16;
constexpr int   kHW     = 512 * 512;               // 2^18
constexpr float kP      = 0.8f;                    // mitigation exponent
constexpr float kLogEps = -4.605170185988091f;     // ln(0.01)

__global__ void init_ws_k(unsigned int* ws) {
    int t = threadIdx.x;
    if (t < 18) ws[t] = 0u;                        // 0 bits == 0.0f for the float accs too
}

__global__ __launch_bounds__(256) void hist_k(const int4* __restrict__ lab4,
                                              unsigned int* __restrict__ hist,
                                              int n4) {
    __shared__ unsigned int lh[4 * 16];            // one sub-histogram per wave
    int t = threadIdx.x;
    if (t < 64) lh[t] = 0u;
    __syncthreads();
    unsigned int* wh = &lh[(t >> 6) << 4];
    int stride = gridDim.x * blockDim.x;
    for (int i = blockIdx.x * blockDim.x + t; i < n4; i += stride) {
        int4 v = lab4[i];
        atomicAdd(&wh[v.x], 1u);
        atomicAdd(&wh[v.y], 1u);
        atomicAdd(&wh[v.z], 1u);
        atomicAdd(&wh[v.w], 1u);
    }
    __syncthreads();
    if (t < 16) atomicAdd(&hist[t], lh[t] + lh[16 + t] + lh[32 + t] + lh[48 + t]);
}

__global__ __launch_bounds__(256) void seesaw_k(const float* __restrict__ cls,
                                                const int*   __restrict__ labels,
                                                const float* __restrict__ cum_in,
                                                const unsigned int* __restrict__ hist,
                                                float* __restrict__ acc) {
    __shared__ float s_plog[16];
    __shared__ float s_red[8];
    int t = threadIdx.x;
    if (t < 16) {
        float cc = fmaxf((float)hist[t] + cum_in[t], 1.0f);   // clip(cum, 1, inf)
        s_plog[t] = kP * __logf(cc);
    }
    __syncthreads();
    float pl[16];
    #pragma unroll
    for (int c = 0; c < 16; ++c) pl[c] = s_plog[c];           // wave-uniform broadcast reads

    long long m0 = (long long)(blockIdx.x * blockDim.x + t) * 4;  // first of 4 pixels
    int b  = (int)(m0 >> 18);                                 // HW = 2^18, divides 4-groups
    int hw = (int)(m0 & (kHW - 1));
    const float* pbase = cls + (long long)b * kC * kHW + hw;

    float4 lv[16];
    #pragma unroll
    for (int c = 0; c < 16; ++c)
        lv[c] = *(const float4*)(pbase + (long long)c * kHW); // 16 B/lane, fully coalesced

    const int4 lab4 = *(const int4*)(labels + m0);
    int labs[4] = {lab4.x, lab4.y, lab4.z, lab4.w};

    float lsum = 0.0f, lcnt = 0.0f;
    #pragma unroll
    for (int p = 0; p < 4; ++p) {
        float l[16];
        #pragma unroll
        for (int c = 0; c < 16; ++c) l[c] = ((const float*)&lv[c])[p];
        int lab = labs[p];

        float m1 = l[0];
        float llab = l[0];                                     // select chain, no dyn index
        #pragma unroll
        for (int c = 1; c < 16; ++c) {
            m1 = fmaxf(m1, l[c]);
            if (c == lab) llab = l[c];
        }
        float s = 0.0f;
        #pragma unroll
        for (int c = 0; c < 16; ++c) s += __expf(l[c] - m1);
        // log(score_mat[c]) = l[c] - K, K = max(llab, m1 + log s + log EPS)
        float K = fmaxf(llab, m1 + __logf(s) + kLogEps);
        float plab = s_plog[lab];                              // LDS gather

        float m2 = -3.0e38f;
        #pragma unroll
        for (int c = 0; c < 16; ++c) {
            // adj = l + log(mit) + log(comp); both clamp to 0 at c==lab -> adj==llab
            float a = l[c] + fminf(0.0f, pl[c] - plab)
                           + fmaxf(0.0f, 2.0f * (l[c] - K));
            l[c] = a;
            m2 = fmaxf(m2, a);
        }
        float s2 = 0.0f;
        #pragma unroll
        for (int c = 0; c < 16; ++c) s2 += __expf(l[c] - m2);
        float nll = m2 + __logf(s2) - llab;                    // -log_softmax(adj)[lab]
        if (lab != 0) { lsum += nll; lcnt += 1.0f; }           // ignore_index = 0
    }

    #pragma unroll
    for (int off = 32; off > 0; off >>= 1) {
        lsum += __shfl_down(lsum, off);
        lcnt += __shfl_down(lcnt, off);
    }
    int wave = t >> 6, lane = t & 63;
    if (lane == 0) { s_red[wave] = lsum; s_red[4 + wave] = lcnt; }
    __syncthreads();
    if (t == 0) {
        atomicAdd(&acc[0], s_red[0] + s_red[1] + s_red[2] + s_red[3]);
        atomicAdd(&acc[1], s_red[4] + s_red[5] + s_red[6] + s_red[7]);
    }
}

__global__ void final_k(const float* __restrict__ acc, float* __restrict__ out) {
    if (threadIdx.x == 0) out[0] = acc[0] / acc[1];
}

extern "C" void kernel_launch(void* const* d_in, const int* in_sizes, int n_in,
                              void* d_out, int out_size, void* d_ws, size_t ws_size,
                              hipStream_t stream) {
    const float* cls    = (const float*)d_in[0];
    const int*   labels = (const int*)d_in[1];
    const float* cum_in = (const float*)d_in[2];
    float* out = (float*)d_out;
    unsigned int* ws = (unsigned int*)d_ws;
    float* acc = (float*)(ws + 16);

    int M  = in_sizes[1];        // 2,097,152 pixels
    int n4 = M / 4;

    init_ws_k<<<1, 64, 0, stream>>>(ws);
    hist_k<<<256, 256, 0, stream>>>((const int4*)labels, ws, n4);
    seesaw_k<<<n4 / 256, 256, 0, stream>>>(cls, labels, cum_in, ws, acc);
    final_k<<<1, 64, 0, stream>>>(acc, out);
}

// Round 2
// 270.498 us; speedup vs baseline: 1.0307x; 1.0307x over previous
//
#include <hip/hip_runtime.h>

// SeesawLoss on MI355X.
// Inputs: d_in[0] = cls_score fp32 (8,16,512,512), d_in[1] = labels i32 (8,512,512),
//         d_in[2] = cum_samples fp32 (16). Output: d_out[0] = scalar loss fp32.
// ws layout (uint32 words): [0..15] class histogram, [16] sum_nll (f32), [17] sum_mask (f32)

constexpr int   kC      = 16;
constexpr int   kHW     = 512 * 512;               // 2^18
constexpr float kP      = 0.8f;                    // mitigation exponent
constexpr float kLogEps = -4.605170185988091f;     // ln(0.01)

__global__ void init_ws_k(unsigned int* ws) {
    int t = threadIdx.x;
    if (t < 18) ws[t] = 0u;                        // 0 bits == 0.0f for the float accs too
}

// Private register counters -> wave shuffle reduce -> block LDS combine -> 16 atomics/block.
// (R1's per-wave LDS atomicAdd serialized 64 random lanes over 16 addresses: ~150us.)
__global__ __launch_bounds__(256) void hist_k(const int4* __restrict__ lab4,
                                              unsigned int* __restrict__ hist,
                                              int n4) {
    int cnt[16];
    #pragma unroll
    for (int c = 0; c < 16; ++c) cnt[c] = 0;
    int stride = gridDim.x * blockDim.x;
    for (int i = blockIdx.x * blockDim.x + threadIdx.x; i < n4; i += stride) {
        int4 v = lab4[i];
        #pragma unroll
        for (int c = 0; c < 16; ++c)
            cnt[c] += (v.x == c) + (v.y == c) + (v.z == c) + (v.w == c);
    }
    #pragma unroll
    for (int c = 0; c < 16; ++c) {
        int x = cnt[c];
        #pragma unroll
        for (int off = 32; off > 0; off >>= 1) x += __shfl_down(x, off);
        cnt[c] = x;
    }
    __shared__ unsigned int sh[4 * 16];
    int wave = threadIdx.x >> 6, lane = threadIdx.x & 63;
    if (lane == 0) {
        #pragma unroll
        for (int c = 0; c < 16; ++c) sh[wave * 16 + c] = (unsigned)cnt[c];
    }
    __syncthreads();
    int t = threadIdx.x;
    if (t < 16) atomicAdd(&hist[t], sh[t] + sh[16 + t] + sh[32 + t] + sh[48 + t]);
}

// Async-DMA staged main pass: 16 channels x 1024 pixels per block into 64 KB LDS via
// global_load_lds width=16 (no VGPR results -> full MLP; R1's register staging was
// batched by the 64-VGPR allocation and went latency-bound at 553 GB/s).
__global__ __launch_bounds__(256, 2) void seesaw_k(const float* __restrict__ cls,
                                                   const int*   __restrict__ labels,
                                                   const float* __restrict__ cum_in,
                                                   const unsigned int* __restrict__ hist,
                                                   float* __restrict__ acc) {
    __shared__ float s_data[16 * 1024];            // [c][1024] pixels, contiguous per chunk
    __shared__ float s_plog[16];
    __shared__ float s_red[8];
    int t = threadIdx.x;
    int wave = t >> 6, lane = t & 63;

    if (t < 16) {
        float cc = fmaxf((float)hist[t] + cum_in[t], 1.0f);   // clip(cum, 1, inf)
        s_plog[t] = kP * __logf(cc);
    }

    long long m0 = (long long)blockIdx.x * 1024;   // block's first pixel (1024 | 2^18: no b-crossing)
    int b  = (int)(m0 >> 18);
    int hw = (int)(m0 & (kHW - 1));
    const float* pbase = cls + (long long)b * kC * kHW + hw;

    // 64 chunks of 256 floats (1 KB); chunk = c*4 + sub covers channel c, pixels sub*256..+255.
    // LDS dest is wave-uniform base + lane*16B (hard constraint) — layout matches exactly.
    #pragma unroll
    for (int i = 0; i < 16; ++i) {
        int chunk = wave * 16 + i;
        int c = chunk >> 2, sub = chunk & 3;
        const float* g = pbase + (long long)c * kHW + sub * 256 + lane * 4;
        __builtin_amdgcn_global_load_lds((const __attribute__((address_space(1))) void*)g,
                                         (__attribute__((address_space(3))) void*)&s_data[chunk * 256],
                                         16, 0, 0);
    }
    const int4 lab4 = *(const int4*)(labels + m0 + (long long)t * 4);
    __syncthreads();                               // drains vmcnt; also publishes s_plog

    float pl[16];
    #pragma unroll
    for (int c = 0; c < 16; ++c) pl[c] = s_plog[c];           // wave-uniform broadcast reads

    float4 lv[16];
    #pragma unroll
    for (int c = 0; c < 16; ++c)
        lv[c] = *(const float4*)&s_data[c * 1024 + t * 4];    // ds_read_b128, conflict-free

    int labs[4] = {lab4.x, lab4.y, lab4.z, lab4.w};

    float lsum = 0.0f, lcnt = 0.0f;
    #pragma unroll
    for (int p = 0; p < 4; ++p) {
        float l[16];
        #pragma unroll
        for (int c = 0; c < 16; ++c) l[c] = ((const float*)&lv[c])[p];
        int lab = labs[p];

        float m1 = l[0];
        float llab = l[0];                                     // select chain, no dyn index
        #pragma unroll
        for (int c = 1; c < 16; ++c) {
            m1 = fmaxf(m1, l[c]);
            if (c == lab) llab = l[c];
        }
        float s = 0.0f;
        #pragma unroll
        for (int c = 0; c < 16; ++c) s += __expf(l[c] - m1);
        // log(score_mat[c]) = l[c] - K, K = max(llab, m1 + log s + log EPS)
        float K = fmaxf(llab, m1 + __logf(s) + kLogEps);
        float plab = s_plog[lab];                              // LDS gather

        float m2 = -3.0e38f;
        #pragma unroll
        for (int c = 0; c < 16; ++c) {
            // adj = l + log(mit) + log(comp); both clamp to 0 at c==lab -> adj==llab
            float a = l[c] + fminf(0.0f, pl[c] - plab)
                           + fmaxf(0.0f, 2.0f * (l[c] - K));
            l[c] = a;
            m2 = fmaxf(m2, a);
        }
        float s2 = 0.0f;
        #pragma unroll
        for (int c = 0; c < 16; ++c) s2 += __expf(l[c] - m2);
        float nll = m2 + __logf(s2) - llab;                    // -log_softmax(adj)[lab]
        if (lab != 0) { lsum += nll; lcnt += 1.0f; }           // ignore_index = 0
    }

    #pragma unroll
    for (int off = 32; off > 0; off >>= 1) {
        lsum += __shfl_down(lsum, off);
        lcnt += __shfl_down(lcnt, off);
    }
    if (lane == 0) { s_red[wave] = lsum; s_red[4 + wave] = lcnt; }
    __syncthreads();
    if (t == 0) {
        atomicAdd(&acc[0], s_red[0] + s_red[1] + s_red[2] + s_red[3]);
        atomicAdd(&acc[1], s_red[4] + s_red[5] + s_red[6] + s_red[7]);
    }
}

__global__ void final_k(const float* __restrict__ acc, float* __restrict__ out) {
    if (threadIdx.x == 0) out[0] = acc[0] / acc[1];
}

extern "C" void kernel_launch(void* const* d_in, const int* in_sizes, int n_in,
                              void* d_out, int out_size, void* d_ws, size_t ws_size,
                              hipStream_t stream) {
    const float* cls    = (const float*)d_in[0];
    const int*   labels = (const int*)d_in[1];
    const float* cum_in = (const float*)d_in[2];
    float* out = (float*)d_out;
    unsigned int* ws = (unsigned int*)d_ws;
    float* acc = (float*)(ws + 16);

    int M  = in_sizes[1];        // 2,097,152 pixels
    int n4 = M / 4;

    init_ws_k<<<1, 64, 0, stream>>>(ws);
    hist_k<<<256, 256, 0, stream>>>((const int4*)labels, ws, n4);
    seesaw_k<<<M / 1024, 256, 0, stream>>>(cls, labels, cum_in, ws, acc);
    final_k<<<1, 64, 0, stream>>>(acc, out);
}

// Round 3
// 208.759 us; speedup vs baseline: 1.3356x; 1.2957x over previous
//
#include <hip/hip_runtime.h>

// SeesawLoss on MI355X.
// Inputs: d_in[0] = cls_score fp32 (8,16,512,512), d_in[1] = labels i32 (8,512,512),
//         d_in[2] = cum_samples fp32 (16). Output: d_out[0] = scalar loss fp32.
// ws layout (uint32 words):
//   [0 .. 255]    histogram, cacheline-spread: count for class c at word c*16
//   [256 .. 1279] 64 accumulator pairs, pair i at words 256 + i*16 (+0 nll, +1 mask)
// R1/R2 lesson: both passes were LATENCY-bound (L3-hit replays equally slow), from
// low MLP x low TLP. R3: register-light 1px/thread + full-occupancy grid + hoisted
// independent loads; no LDS staging; atomics spread across cachelines.

constexpr int   kC      = 16;
constexpr int   kHW     = 512 * 512;               // 2^18
constexpr float kP      = 0.8f;                    // mitigation exponent
constexpr float kLogEps = -4.605170185988091f;     // ln(0.01)
constexpr int   kNAcc   = 64;                      // spread accumulator pairs

__global__ __launch_bounds__(256) void init_ws_k(unsigned int* ws) {
    for (int i = threadIdx.x; i < 256 + kNAcc * 16; i += 256) ws[i] = 0u;
}

// 256 blocks; block b covers contiguous 32 KB of labels (2048 int4). 8 independent
// fully-unrolled int4 loads/thread -> 32 KB in flight per CU even at 1 block/CU.
__global__ __launch_bounds__(256) void hist_k(const int4* __restrict__ lab4,
                                              unsigned int* __restrict__ histp) {
    int base = blockIdx.x * 2048 + threadIdx.x;
    int4 v[8];
    #pragma unroll
    for (int j = 0; j < 8; ++j) v[j] = lab4[base + j * 256];   // iter j: contiguous 4 KB
    int cnt[16];
    #pragma unroll
    for (int c = 0; c < 16; ++c) cnt[c] = 0;
    #pragma unroll
    for (int j = 0; j < 8; ++j) {
        #pragma unroll
        for (int c = 0; c < 16; ++c)
            cnt[c] += (v[j].x == c) + (v[j].y == c) + (v[j].z == c) + (v[j].w == c);
    }
    #pragma unroll
    for (int c = 0; c < 16; ++c) {
        int x = cnt[c];
        #pragma unroll
        for (int off = 32; off > 0; off >>= 1) x += __shfl_down(x, off);
        cnt[c] = x;
    }
    __shared__ unsigned int sh[4 * 16];
    int wave = threadIdx.x >> 6, lane = threadIdx.x & 63;
    if (lane == 0) {
        #pragma unroll
        for (int c = 0; c < 16; ++c) sh[wave * 16 + c] = (unsigned)cnt[c];
    }
    __syncthreads();
    int t = threadIdx.x;
    if (t < 16)   // per-class slots are 64 B apart -> 256 atomics per line, not 4096
        atomicAdd(&histp[t * 16], sh[t] + sh[16 + t] + sh[32 + t] + sh[48 + t]);
}

// 1 pixel/thread: 16 channel loads = 16 data VGPRs, all independent & hoisted.
// 8192 blocks x 256 threads -> full occupancy; no LDS staging.
__global__ __launch_bounds__(256, 4) void seesaw_k(const float* __restrict__ cls,
                                                   const int*   __restrict__ labels,
                                                   const float* __restrict__ cum_in,
                                                   const unsigned int* __restrict__ histp,
                                                   float* __restrict__ ws) {
    __shared__ float s_plog[16];
    __shared__ float s_red[8];
    int t = threadIdx.x;
    if (t < 16) {
        float cc = fmaxf((float)histp[t * 16] + cum_in[t], 1.0f);  // clip(cum, 1, inf)
        s_plog[t] = kP * __logf(cc);
    }
    __syncthreads();

    int px = blockIdx.x * 256 + t;                 // grid exactly covers M
    int b  = px >> 18;
    int hw = px & (kHW - 1);
    const float* pbase = cls + (long long)b * kC * kHW + hw;

    float l[16];
    #pragma unroll
    for (int c = 0; c < 16; ++c) l[c] = pbase[(long long)c * kHW];  // 16 outstanding dwords
    int lab = labels[px];

    float pl[16];
    #pragma unroll
    for (int c = 0; c < 16; ++c) pl[c] = s_plog[c];                 // wave-uniform broadcast

    float m1 = l[0];
    float llab = l[0];                                              // select chain, no dyn index
    #pragma unroll
    for (int c = 1; c < 16; ++c) {
        m1 = fmaxf(m1, l[c]);
        if (c == lab) llab = l[c];
    }
    float s = 0.0f;
    #pragma unroll
    for (int c = 0; c < 16; ++c) s += __expf(l[c] - m1);
    // log(score_mat[c]) = l[c] - K, K = max(llab, m1 + log s + log EPS)
    float K = fmaxf(llab, m1 + __logf(s) + kLogEps);
    float plab = s_plog[lab];                                       // LDS gather

    float m2 = -3.0e38f;
    #pragma unroll
    for (int c = 0; c < 16; ++c) {
        // adj = l + log(mit) + log(comp); both clamp to 0 at c==lab -> adj==llab
        float a = l[c] + fminf(0.0f, pl[c] - plab)
                       + fmaxf(0.0f, 2.0f * (l[c] - K));
        l[c] = a;
        m2 = fmaxf(m2, a);
    }
    float s2 = 0.0f;
    #pragma unroll
    for (int c = 0; c < 16; ++c) s2 += __expf(l[c] - m2);
    float nll = m2 + __logf(s2) - llab;                             // -log_softmax(adj)[lab]

    float lsum = 0.0f, lcnt = 0.0f;
    if (lab != 0) { lsum = nll; lcnt = 1.0f; }                      // ignore_index = 0
    #pragma unroll
    for (int off = 32; off > 0; off >>= 1) {
        lsum += __shfl_down(lsum, off);
        lcnt += __shfl_down(lcnt, off);
    }
    int wave = t >> 6, lane = t & 63;
    if (lane == 0) { s_red[wave] = lsum; s_red[4 + wave] = lcnt; }
    __syncthreads();
    if (t == 0) {
        float* pair = ws + 256 + (blockIdx.x & (kNAcc - 1)) * 16;   // 64 B-spread pairs
        atomicAdd(&pair[0], s_red[0] + s_red[1] + s_red[2] + s_red[3]);
        atomicAdd(&pair[1], s_red[4] + s_red[5] + s_red[6] + s_red[7]);
    }
}

__global__ void final_k(const float* __restrict__ ws, float* __restrict__ out) {
    int t = threadIdx.x;                           // one wave
    float a = (t < kNAcc) ? ws[256 + t * 16]     : 0.0f;
    float b = (t < kNAcc) ? ws[256 + t * 16 + 1] : 0.0f;
    #pragma unroll
    for (int off = 32; off > 0; off >>= 1) {
        a += __shfl_down(a, off);
        b += __shfl_down(b, off);
    }
    if (t == 0) out[0] = a / b;
}

extern "C" void kernel_launch(void* const* d_in, const int* in_sizes, int n_in,
                              void* d_out, int out_size, void* d_ws, size_t ws_size,
                              hipStream_t stream) {
    const float* cls    = (const float*)d_in[0];
    const int*   labels = (const int*)d_in[1];
    const float* cum_in = (const float*)d_in[2];
    float* out = (float*)d_out;
    unsigned int* ws = (unsigned int*)d_ws;

    int M  = in_sizes[1];        // 2,097,152 pixels
    int n4 = M / 4;

    init_ws_k<<<1, 256, 0, stream>>>(ws);
    hist_k<<<n4 / 2048, 256, 0, stream>>>((const int4*)labels, ws);
    seesaw_k<<<M / 256, 256, 0, stream>>>(cls, labels, cum_in, ws, (float*)ws);
    final_k<<<1, 64, 0, stream>>>((const float*)ws, out);
}